// Round 1
// baseline (157.955 us; speedup 1.0000x reference)
//
#include <hip/hip_runtime.h>
#include <hip/hip_bf16.h>

typedef __attribute__((ext_vector_type(8))) short short8;
typedef __attribute__((ext_vector_type(4))) float floatx4;

#define NROWS 4096
#define NHALF 2048
#define DDIM  128
#define LDST  136                 // LDS row stride in ushorts (128 + 8 pad -> 272B, 2-way = free)
#define SQRT_SCALE 2.6857914f     // sqrt(1/(0.2*ln2)) ; dot of stored z == (sim/T)*log2(e)
#define LN2 0.69314718056f

// ws float layout: [0]=loss acc, [1]=all_num, [64 .. 64+16384) = rowsum
#define WS_ROWSUM_OFF 64
#define WS_Z_BYTE_OFF 65792       // (64+16384)*4, 16B aligned

__device__ inline unsigned short f2bf(float f) {
    unsigned u = __builtin_bit_cast(unsigned, f);
    u += 0x7fffu + ((u >> 16) & 1u);          // RNE
    return (unsigned short)(u >> 16);
}
__device__ inline float bf2f(unsigned short b) {
    unsigned u = ((unsigned)b) << 16;
    return __builtin_bit_cast(float, u);
}

// ---------------- kernel 1: normalize + scale + cast to bf16; zero accumulators; all_num ----
__global__ __launch_bounds__(256) void k_norm(const float* __restrict__ emb_i,
                                              const float* __restrict__ emb_j,
                                              const float* __restrict__ jv,
                                              float* __restrict__ wsf,
                                              unsigned short* __restrict__ z) {
    int bx = blockIdx.x, tid = threadIdx.x;
    if (bx == 4096) {                         // all_num = sum(joint_valid)
        __shared__ float sred[256];
        float s = 0.f;
        #pragma unroll
        for (int i = 0; i < 8; ++i) s += jv[tid + 256 * i];
        sred[tid] = s; __syncthreads();
        for (int off = 128; off > 0; off >>= 1) {
            if (tid < off) sred[tid] += sred[tid + off];
            __syncthreads();
        }
        if (tid == 0) wsf[1] = sred[0];
        return;
    }
    int gid = bx * 256 + tid;                 // zero acc + rowsum (ws is poisoned 0xAA each call)
    if (gid == 0) wsf[0] = 0.f;
    if (gid >= WS_ROWSUM_OFF && gid < WS_ROWSUM_OFF + 16384) wsf[gid] = 0.f;

    int wave = tid >> 6, lane = tid & 63;
    int r = bx * 4 + wave;                    // global row 0..16383
    int l = r >> 12, n = r & 4095;
    const float* src = (n < NHALF) ? (emb_i + ((size_t)l * NHALF + n) * DDIM)
                                   : (emb_j + ((size_t)l * NHALF + (n - NHALF)) * DDIM);
    float2 v = *(const float2*)(src + lane * 2);
    float ss = v.x * v.x + v.y * v.y;
    #pragma unroll
    for (int off = 1; off < 64; off <<= 1) ss += __shfl_xor(ss, off);
    float inv = SQRT_SCALE / fmaxf(sqrtf(ss), 1e-12f);
    unsigned pack = ((unsigned)f2bf(v.y * inv) << 16) | (unsigned)f2bf(v.x * inv);
    *(unsigned*)(z + (size_t)r * DDIM + lane * 2) = pack;
}

// ---------------- kernel 2: fused sim GEMM + rowwise sum of exp2 ---------------------------
// grid 256: l(4) x rowtile(16, 256 rows) x coltile(4, 1024 cols). 4 waves, 64 rows/wave.
__global__ __launch_bounds__(256, 1) void k_sim(const unsigned short* __restrict__ z,
                                                float* __restrict__ rowsum) {
    __shared__ __align__(16) unsigned short lds[128 * LDST];
    int bx = blockIdx.x, tid = threadIdx.x;
    int l = bx & 3, rb = (bx >> 2) & 15, cb = bx >> 6;
    int wave = tid >> 6, lane = tid & 63, m = lane & 15, quad = lane >> 4;
    const unsigned short* zl = z + (size_t)l * NROWS * DDIM;
    int wr0 = rb * 256 + wave * 64;

    short8 a[4][4];                           // 4 row-subtiles x 4 k-steps, resident in VGPRs
    #pragma unroll
    for (int rs = 0; rs < 4; ++rs) {
        const unsigned short* p = zl + (size_t)(wr0 + rs * 16 + m) * DDIM + quad * 8;
        #pragma unroll
        for (int kk = 0; kk < 4; ++kk) a[rs][kk] = *(const short8*)(p + kk * 32);
    }
    floatx4 rsum[4];
    #pragma unroll
    for (int rs = 0; rs < 4; ++rs) rsum[rs] = (floatx4){0.f, 0.f, 0.f, 0.f};

    for (int stg = 0; stg < 8; ++stg) {       // 8 x 128-col LDS tiles
        int cg0 = cb * 1024 + stg * 128;
        __syncthreads();
        #pragma unroll
        for (int i = 0; i < 8; ++i) {         // stage 128x128 bf16 (32KB), 16B chunks
            int chunk = tid + 256 * i;
            int col = chunk >> 4, off = chunk & 15;
            uint4 d = *(const uint4*)(zl + (size_t)(cg0 + col) * DDIM + off * 8);
            *(uint4*)&lds[col * LDST + off * 8] = d;
        }
        __syncthreads();
        #pragma unroll
        for (int cs = 0; cs < 8; ++cs) {      // 16-col subtiles
            const unsigned short* lp = &lds[(cs * 16 + m) * LDST + quad * 8];
            short8 b0 = *(const short8*)(lp);
            short8 b1 = *(const short8*)(lp + 32);
            short8 b2 = *(const short8*)(lp + 64);
            short8 b3 = *(const short8*)(lp + 96);
            #pragma unroll
            for (int rs = 0; rs < 4; ++rs) {
                floatx4 acc = (floatx4){0.f, 0.f, 0.f, 0.f};
                acc = __builtin_amdgcn_mfma_f32_16x16x32_bf16(a[rs][0], b0, acc, 0, 0, 0);
                acc = __builtin_amdgcn_mfma_f32_16x16x32_bf16(a[rs][1], b1, acc, 0, 0, 0);
                acc = __builtin_amdgcn_mfma_f32_16x16x32_bf16(a[rs][2], b2, acc, 0, 0, 0);
                acc = __builtin_amdgcn_mfma_f32_16x16x32_bf16(a[rs][3], b3, acc, 0, 0, 0);
                #pragma unroll
                for (int c = 0; c < 4; ++c)
                    rsum[rs][c] += __builtin_amdgcn_exp2f(acc[c]);
            }
        }
    }
    // reduce across the 16 column-lanes (bits 0..3 of lane)
    #pragma unroll
    for (int off = 1; off < 16; off <<= 1)
        #pragma unroll
        for (int rs = 0; rs < 4; ++rs)
            #pragma unroll
            for (int c = 0; c < 4; ++c)
                rsum[rs][c] += __shfl_xor(rsum[rs][c], off);
    if (m == 0) {                             // lanes 0,16,32,48: rows wr0 + rs*16 + quad*4 + c
        #pragma unroll
        for (int rs = 0; rs < 4; ++rs)
            #pragma unroll
            for (int c = 0; c < 4; ++c) {
                int rg = wr0 + rs * 16 + quad * 4 + c;
                atomicAdd(&rowsum[l * NROWS + rg], rsum[rs][c]);
            }
    }
}

// ---------------- kernel 3: per-row loss = ln(denom) - pos/T, weighted ---------------------
__global__ __launch_bounds__(256) void k_loss(const unsigned short* __restrict__ z,
                                              const float* __restrict__ jv,
                                              const float* __restrict__ rowsum,
                                              float* __restrict__ wsf) {
    int tid = threadIdx.x, lane = tid & 63, wave = tid >> 6;
    int w = blockIdx.x * 4 + wave;            // 0..4095, 4 rows each
    float local = 0.f;
    for (int i = 0; i < 4; ++i) {
        int r = w * 4 + i;
        int n = r & 4095;
        int rp = r ^ 2048;                    // partner row (same l, flips half)
        unsigned ua = *(const unsigned*)(z + (size_t)r  * DDIM + lane * 2);
        unsigned ub = *(const unsigned*)(z + (size_t)rp * DDIM + lane * 2);
        float a0 = __builtin_bit_cast(float, ua << 16);
        float a1 = __builtin_bit_cast(float, ua & 0xffff0000u);
        float c0 = __builtin_bit_cast(float, ub << 16);
        float c1 = __builtin_bit_cast(float, ub & 0xffff0000u);
        float dd = a0 * a0 + a1 * a1;         // scaled self-dot (exp2 arg of diagonal)
        float dp = a0 * c0 + a1 * c1;         // scaled positive dot
        #pragma unroll
        for (int off = 1; off < 64; off <<= 1) {
            dd += __shfl_xor(dd, off);
            dp += __shfl_xor(dp, off);
        }
        if (lane == 0) {
            float denom = rowsum[r] - __builtin_amdgcn_exp2f(dd);
            float contrib = LN2 * (__builtin_amdgcn_logf(denom) - dp);  // ln(denom) - pos/T
            local += contrib * jv[n & (NHALF - 1)];
        }
    }
    if (lane == 0) atomicAdd(&wsf[0], local);
}

// ---------------- kernel 4: final scalar ---------------------------------------------------
__global__ void k_final(const float* __restrict__ wsf, float* __restrict__ out) {
    if (threadIdx.x == 0) out[0] = wsf[0] / (2.f * wsf[1]);
}

extern "C" void kernel_launch(void* const* d_in, const int* in_sizes, int n_in,
                              void* d_out, int out_size, void* d_ws, size_t ws_size,
                              hipStream_t stream) {
    const float* emb_i = (const float*)d_in[0];
    const float* emb_j = (const float*)d_in[1];
    const float* jv    = (const float*)d_in[2];
    float* wsf = (float*)d_ws;
    float* rowsum = wsf + WS_ROWSUM_OFF;
    unsigned short* z = (unsigned short*)((char*)d_ws + WS_Z_BYTE_OFF);
    float* out = (float*)d_out;

    k_norm <<<4097, 256, 0, stream>>>(emb_i, emb_j, jv, wsf, z);
    k_sim  <<<256,  256, 0, stream>>>(z, rowsum);
    k_loss <<<1024, 256, 0, stream>>>(z, jv, rowsum, wsf);
    k_final<<<1,    64,  0, stream>>>(wsf, out);
}

// Round 2
// 99.833 us; speedup vs baseline: 1.5822x; 1.5822x over previous
//
#include <hip/hip_runtime.h>
#include <hip/hip_bf16.h>

typedef __attribute__((ext_vector_type(8))) short short8;
typedef __attribute__((ext_vector_type(4))) float floatx4;

#define NROWS 4096
#define NHALF 2048
#define DDIM  128
#define LDST  136                 // LDS row stride in ushorts (128 + 8 pad -> 272B, 2-way = free)
#define SQRT_SCALE 2.6857914f     // sqrt(1/(0.2*ln2)) ; dot of stored z == (sim/T)*log2(e)
#define LN2 0.69314718056f

// ws float layout: [0]=loss acc, [1]=all_num,
// rowsum [64, 64+16384), diag [16448, +16384), pos [32832, +16384)
#define WS_ROWSUM_OFF 64
#define WS_DIAG_OFF   16448
#define WS_POS_OFF    32832
#define WS_Z_BYTE_OFF 196864      // (64+3*16384)*4, 16B aligned

__device__ inline unsigned short f2bf(float f) {
    unsigned u = __builtin_bit_cast(unsigned, f);
    u += 0x7fffu + ((u >> 16) & 1u);          // RNE
    return (unsigned short)(u >> 16);
}

// ---------------- kernel 1: normalize + scale + cast to bf16; zero accumulators; all_num ----
__global__ __launch_bounds__(256) void k_norm(const float* __restrict__ emb_i,
                                              const float* __restrict__ emb_j,
                                              const float* __restrict__ jv,
                                              float* __restrict__ wsf,
                                              unsigned short* __restrict__ z) {
    int bx = blockIdx.x, tid = threadIdx.x;
    if (bx == 4096) {                         // all_num = sum(joint_valid)
        __shared__ float sred[256];
        float s = 0.f;
        #pragma unroll
        for (int i = 0; i < 8; ++i) s += jv[tid + 256 * i];
        sred[tid] = s; __syncthreads();
        for (int off = 128; off > 0; off >>= 1) {
            if (tid < off) sred[tid] += sred[tid + off];
            __syncthreads();
        }
        if (tid == 0) wsf[1] = sred[0];
        return;
    }
    int gid = bx * 256 + tid;                 // zero loss acc + rowsum (ws poisoned each call)
    if (gid == 0) wsf[0] = 0.f;
    if (gid >= WS_ROWSUM_OFF && gid < WS_ROWSUM_OFF + 16384) wsf[gid] = 0.f;

    int wave = tid >> 6, lane = tid & 63;
    int r = bx * 4 + wave;                    // global row 0..16383
    int l = r >> 12, n = r & 4095;
    const float* src = (n < NHALF) ? (emb_i + ((size_t)l * NHALF + n) * DDIM)
                                   : (emb_j + ((size_t)l * NHALF + (n - NHALF)) * DDIM);
    float2 v = *(const float2*)(src + lane * 2);
    float ss = v.x * v.x + v.y * v.y;
    #pragma unroll
    for (int off = 1; off < 64; off <<= 1) ss += __shfl_xor(ss, off);
    float inv = SQRT_SCALE / fmaxf(sqrtf(ss), 1e-12f);
    unsigned pack = ((unsigned)f2bf(v.y * inv) << 16) | (unsigned)f2bf(v.x * inv);
    *(unsigned*)(z + (size_t)r * DDIM + lane * 2) = pack;
}

// ---------------- kernel 2: fused sim GEMM + rowwise sum of exp2 + diag/pos extraction -----
// grid 512: l(4) x rowtile(16, 256 rows) x coltile(8, 512 cols). 4 waves, 64 rows/wave.
// 2 blocks/CU (VGPR <= 256, LDS 34KB) -> 2 waves/SIMD latency hiding.
__global__ __launch_bounds__(256) void k_sim(const unsigned short* __restrict__ z,
                                             float* __restrict__ rowsum,
                                             float* __restrict__ diag,
                                             float* __restrict__ pos) {
    __shared__ __align__(16) unsigned short lds[128 * LDST];
    int bx = blockIdx.x, tid = threadIdx.x;
    int l = bx & 3, rb = (bx >> 2) & 15, cb = bx >> 6;
    int wave = tid >> 6, lane = tid & 63, m = lane & 15, quad = lane >> 4;
    const unsigned short* zl = z + (size_t)l * NROWS * DDIM;
    int l4 = l * NROWS;
    int wr0 = rb * 256 + wave * 64;

    short8 a[4][4];                           // 4 row-subtiles x 4 k-steps, resident in VGPRs
    #pragma unroll
    for (int rs = 0; rs < 4; ++rs) {
        const unsigned short* p = zl + (size_t)(wr0 + rs * 16 + m) * DDIM + quad * 8;
        #pragma unroll
        for (int kk = 0; kk < 4; ++kk) a[rs][kk] = *(const short8*)(p + kk * 32);
    }
    floatx4 rsum[4];
    #pragma unroll
    for (int rs = 0; rs < 4; ++rs) rsum[rs] = (floatx4){0.f, 0.f, 0.f, 0.f};

    for (int stg = 0; stg < 4; ++stg) {       // 4 x 128-col LDS tiles (512 cols per block)
        int cg0 = cb * 512 + stg * 128;
        __syncthreads();
        #pragma unroll
        for (int i = 0; i < 8; ++i) {         // stage 128x128 bf16 (32KB), 16B chunks
            int chunk = tid + 256 * i;
            int col = chunk >> 4, off = chunk & 15;
            uint4 d = *(const uint4*)(zl + (size_t)(cg0 + col) * DDIM + off * 8);
            *(uint4*)&lds[col * LDST + off * 8] = d;
        }
        __syncthreads();
        #pragma unroll
        for (int cs = 0; cs < 8; ++cs) {      // 16-col subtiles
            int ct = cg0 + cs * 16;           // tile column base (wave-uniform)
            const unsigned short* lp = &lds[(cs * 16 + m) * LDST + quad * 8];
            short8 b0 = *(const short8*)(lp);
            short8 b1 = *(const short8*)(lp + 32);
            short8 b2 = *(const short8*)(lp + 64);
            short8 b3 = *(const short8*)(lp + 96);
            #pragma unroll
            for (int rs = 0; rs < 4; ++rs) {
                floatx4 acc = (floatx4){0.f, 0.f, 0.f, 0.f};
                acc = __builtin_amdgcn_mfma_f32_16x16x32_bf16(a[rs][0], b0, acc, 0, 0, 0);
                acc = __builtin_amdgcn_mfma_f32_16x16x32_bf16(a[rs][1], b1, acc, 0, 0, 0);
                acc = __builtin_amdgcn_mfma_f32_16x16x32_bf16(a[rs][2], b2, acc, 0, 0, 0);
                acc = __builtin_amdgcn_mfma_f32_16x16x32_bf16(a[rs][3], b3, acc, 0, 0, 0);
                int rowbase = wr0 + rs * 16;
                bool isdiag = (ct == rowbase);
                bool ispos  = (ct == (rowbase ^ 2048));
                if (isdiag || ispos) {        // rare, wave-uniform branch
                    int c = m - (quad << 2);  // lane holds (row=rowbase+m) iff quad*4+c == m
                    if (c >= 0 && c < 4) {
                        float v = acc[c];
                        float* dst = isdiag ? &diag[l4 + rowbase + m]
                                            : &pos[l4 + rowbase + m];
                        *dst = v;             // pre-exp2 arg; single writer per element
                    }
                }
                #pragma unroll
                for (int c = 0; c < 4; ++c)
                    rsum[rs][c] += __builtin_amdgcn_exp2f(acc[c]);
            }
        }
    }
    // reduce across the 16 column-lanes (bits 0..3 of lane)
    #pragma unroll
    for (int off = 1; off < 16; off <<= 1)
        #pragma unroll
        for (int rs = 0; rs < 4; ++rs)
            #pragma unroll
            for (int c = 0; c < 4; ++c)
                rsum[rs][c] += __shfl_xor(rsum[rs][c], off);
    if (m == 0) {                             // lanes 0,16,32,48: rows wr0 + rs*16 + quad*4 + c
        #pragma unroll
        for (int rs = 0; rs < 4; ++rs)
            #pragma unroll
            for (int c = 0; c < 4; ++c) {
                int rg = wr0 + rs * 16 + quad * 4 + c;
                atomicAdd(&rowsum[l4 + rg], rsum[rs][c]);
            }
    }
}

// ---------------- kernel 3: per-row loss from rowsum/diag/pos, 1 atomic per block ----------
__global__ __launch_bounds__(256) void k_loss(const float* __restrict__ jv,
                                              const float* __restrict__ rowsum,
                                              const float* __restrict__ diag,
                                              const float* __restrict__ pos,
                                              float* __restrict__ wsf) {
    __shared__ float sred[256];
    int tid = threadIdx.x;
    int r = blockIdx.x * 256 + tid;           // 64 blocks x 256 = 16384 rows
    int n = r & 4095;
    float denom = rowsum[r] - __builtin_amdgcn_exp2f(diag[r]);  // exact: same fp32 value
    float contrib = LN2 * (__builtin_amdgcn_logf(denom) - pos[r]); // logf = v_log_f32 = log2
    float local = contrib * jv[n & (NHALF - 1)];
    sred[tid] = local; __syncthreads();
    for (int off = 128; off > 0; off >>= 1) {
        if (tid < off) sred[tid] += sred[tid + off];
        __syncthreads();
    }
    if (tid == 0) atomicAdd(&wsf[0], sred[0]);
}

// ---------------- kernel 4: final scalar ---------------------------------------------------
__global__ void k_final(const float* __restrict__ wsf, float* __restrict__ out) {
    if (threadIdx.x == 0) out[0] = wsf[0] / (2.f * wsf[1]);
}

extern "C" void kernel_launch(void* const* d_in, const int* in_sizes, int n_in,
                              void* d_out, int out_size, void* d_ws, size_t ws_size,
                              hipStream_t stream) {
    const float* emb_i = (const float*)d_in[0];
    const float* emb_j = (const float*)d_in[1];
    const float* jv    = (const float*)d_in[2];
    float* wsf    = (float*)d_ws;
    float* rowsum = wsf + WS_ROWSUM_OFF;
    float* diag   = wsf + WS_DIAG_OFF;
    float* pos    = wsf + WS_POS_OFF;
    unsigned short* z = (unsigned short*)((char*)d_ws + WS_Z_BYTE_OFF);
    float* out = (float*)d_out;

    k_norm <<<4097, 256, 0, stream>>>(emb_i, emb_j, jv, wsf, z);
    k_sim  <<<512,  256, 0, stream>>>(z, rowsum, diag, pos);
    k_loss <<<64,   256, 0, stream>>>(jv, rowsum, diag, pos, wsf);
    k_final<<<1,    64,  0, stream>>>(wsf, out);
}